// Round 6
// baseline (10825.260 us; speedup 1.0000x reference)
//
#include <hip/hip_runtime.h>
#include <hip/hip_fp16.h>

// HybridQLSTM: B=64, S=2048, D=4, H=256, NCLS=2.
// R6: 512 threads/block (2 threads per unit) => 256-VGPR budget at 2 waves/EU.
// i,f,g gate weights truly register-resident (192 half2); o-gate streamed from
// L2 (kept resident by making hbuf writes nontemporal); h via broadcast LDS.

#define BB 64
#define SS 2048
#define HH 256

typedef _Float16 f16;

union U16 { uint4 u4; __half2 h[4]; float f[4]; f16 e[8]; };
union U8  { uint2 u2; __half2 h[2]; };

__device__ __forceinline__ float psum2(float x){
#if __has_builtin(__builtin_amdgcn_mov_dpp)
  // quad_perm [1,0,3,2]: swap pair lanes (xor 1)
  x += __int_as_float(__builtin_amdgcn_mov_dpp(__float_as_int(x), 0xB1, 0xf, 0xf, true));
#else
  x += __shfl_xor(x, 1, 64);
#endif
  return x;
}

__device__ __forceinline__ float sigmf_(float x){ return 1.f/(1.f + __expf(-x)); }
__device__ __forceinline__ float tanhf_(float x){
  x = fminf(fmaxf(x, -15.f), 15.f);
  float e = __expf(2.f*x);
  return (e - 1.f)/(e + 1.f);
}

// ----------------------------------------------------------------------------
// prep job space: feat 131072 | wso 8192 | wxb 256 | w1t 32768 | w2t 32768 |
// w3p 256  => 205312 = 802*256.
// wso[j*512 + t] (uint4): o-gate row 768+u, cols kh*128 + j*8 .. +8 (f16)
// wxb[u*3+0]: w_ih rows u (i) & u+256 (f) packed f16; [1]: rows 512+u,768+u;
// [2]: bias float4 (i,f,g,o).
// ----------------------------------------------------------------------------
__global__ void prep_kernel(
    const float* __restrict__ x, const float* __restrict__ conv_w, const float* __restrict__ conv_b,
    const float* __restrict__ w_ih, const float* __restrict__ w_hh,
    const float* __restrict__ b_ih, const float* __restrict__ b_hh,
    const float* __restrict__ w1, const float* __restrict__ w2, const float* __restrict__ w3,
    f16* __restrict__ feat2, uint4* __restrict__ wso, uint4* __restrict__ wxb,
    f16* __restrict__ w1t, f16* __restrict__ w2t, f16* __restrict__ w3p)
{
  int id = blockIdx.x*256 + threadIdx.x;
  if (id < BB*SS){
    float4 xv = *(const float4*)(x + (size_t)id*4);
    float f0 = sigmf_(xv.x*conv_w[0] + conv_b[0]);
    float f1 = sigmf_(xv.y*conv_w[1] + conv_b[1]);
    float f2 = sigmf_(xv.z*conv_w[2] + conv_b[2]);
    float f3 = sigmf_(xv.w*conv_w[3] + conv_b[3]);
    f16* o = feat2 + (size_t)id*4;
    o[0]=(f16)f0; o[1]=(f16)f1; o[2]=(f16)f2; o[3]=(f16)f3;
    return;
  }
  id -= BB*SS;
  if (id < 8192){
    int j = id >> 9, t = id & 511;
    int u = t >> 1, kh = t & 1;
    const float* src = w_hh + (size_t)(768+u)*256 + kh*128 + j*8;
    U16 o;
    #pragma unroll
    for (int k=0;k<8;k++) o.e[k] = (f16)src[k];
    wso[id] = o.u4;
    return;
  }
  id -= 8192;
  if (id < 256){
    int u = id;
    U16 a, b, c;
    #pragma unroll
    for (int k=0;k<4;k++){ a.e[k] = (f16)w_ih[(size_t)u*4+k];
                           a.e[4+k] = (f16)w_ih[(size_t)(u+256)*4+k]; }
    #pragma unroll
    for (int k=0;k<4;k++){ b.e[k] = (f16)w_ih[(size_t)(u+512)*4+k];
                           b.e[4+k] = (f16)w_ih[(size_t)(u+768)*4+k]; }
    #pragma unroll
    for (int k=0;k<4;k++) c.f[k] = b_ih[u+256*k] + b_hh[u+256*k];
    wxb[u*3+0] = a.u4; wxb[u*3+1] = b.u4; wxb[u*3+2] = c.u4;
    return;
  }
  id -= 256;
  if (id < 32768){
    int kp = id >> 8, n = id & 255;
    w1t[(size_t)id*2+0] = (f16)w1[(size_t)n*256 + 2*kp];
    w1t[(size_t)id*2+1] = (f16)w1[(size_t)n*256 + 2*kp+1];
    return;
  }
  id -= 32768;
  if (id < 32768){
    int kp = id >> 8, n = id & 255;
    w2t[(size_t)id*2+0] = (f16)w2[(size_t)n*256 + 2*kp];
    w2t[(size_t)id*2+1] = (f16)w2[(size_t)n*256 + 2*kp+1];
    return;
  }
  id -= 32768;
  if (id < 256){
    int kp = id >> 1, cls = id & 1;
    w3p[(size_t)id*2+0] = (f16)w3[(size_t)cls*256 + 2*kp];
    w3p[(size_t)id*2+1] = (f16)w3[(size_t)cls*256 + 2*kp+1];
  }
}

// ----------------------------------------------------------------------------
// LSTM: 64 blocks x 512 threads. Thread t: unit u=t>>1, col-half kh=t&1.
// ----------------------------------------------------------------------------
__global__ __attribute__((amdgpu_flat_work_group_size(512,512), amdgpu_waves_per_eu(2,2)))
void lstm_kernel(
    const float* __restrict__ w_hh, const f16* __restrict__ feat2,
    const uint4* __restrict__ wso, const uint4* __restrict__ wxb,
    f16* __restrict__ hbuf)
{
  const int b = blockIdx.x, t = threadIdx.x;
  const int u = t >> 1, kh = t & 1;
  __shared__ __align__(16) __half hsh[2][264];   // double-buffered h (+pad)

  // resident i,f,g weights: rows u, 256+u, 512+u; cols [kh*128, kh*128+128)
  __half2 wri[64], wrf[64], wrg[64];
  {
    const float* si = w_hh + (size_t)u*256       + kh*128;
    const float* sf = w_hh + (size_t)(256+u)*256 + kh*128;
    const float* sg = w_hh + (size_t)(512+u)*256 + kh*128;
    #pragma unroll
    for (int j=0;j<32;j++){
      float4 a = *(const float4*)(si + j*4);
      wri[j*2+0] = __floats2half2_rn(a.x,a.y); wri[j*2+1] = __floats2half2_rn(a.z,a.w);
      a = *(const float4*)(sf + j*4);
      wrf[j*2+0] = __floats2half2_rn(a.x,a.y); wrf[j*2+1] = __floats2half2_rn(a.z,a.w);
      a = *(const float4*)(sg + j*4);
      wrg[j*2+0] = __floats2half2_rn(a.x,a.y); wrg[j*2+1] = __floats2half2_rn(a.z,a.w);
    }
  }
  U16 wxA, wxB, bsv;
  wxA.u4 = wxb[u*3+0]; wxB.u4 = wxb[u*3+1]; bsv.u4 = wxb[u*3+2];

  if (t < 256) hsh[0][t] = __float2half(0.f);
  __syncthreads();

  const uint4* wsoT = wso + t;                 // + j*512 per chunk
  const f16* fpt = feat2 + (size_t)b*SS*4;
  f16* hrow = hbuf + (size_t)b*SS*HH;
  float cst = 0.f;
  int buf = 0;
  const __half2 z2 = __floats2half2_rn(0.f,0.f);

  for (int s=0; s<SS; ++s){
    const uint4* hq = (const uint4*)(&hsh[buf][kh*128]);
    __half2 ai = z2, af = z2, ag = z2, ao = z2;
    float a0=0.f, a1=0.f, a2=0.f, a3=0.f;
    #pragma unroll
    for (int j=0;j<16;j++){
      U16 hv; hv.u4 = hq[j];
      U16 ov; ov.u4 = wsoT[(size_t)j*512];
      #pragma unroll
      for (int p=0;p<4;p++){
        ai = __hfma2(wri[j*4+p], hv.h[p], ai);
        af = __hfma2(wrf[j*4+p], hv.h[p], af);
        ag = __hfma2(wrg[j*4+p], hv.h[p], ag);
        ao = __hfma2(ov.h[p],    hv.h[p], ao);
      }
      if ((j&3)==3){  // flush every 32 terms
        a0 += __low2float(ai) + __high2float(ai); ai = z2;
        a1 += __low2float(af) + __high2float(af); af = z2;
        a2 += __low2float(ag) + __high2float(ag); ag = z2;
        a3 += __low2float(ao) + __high2float(ao); ao = z2;
      }
    }
    // pair reduction (lanes t, t^1): replicated in both
    a0 = psum2(a0); a1 = psum2(a1); a2 = psum2(a2); a3 = psum2(a3);

    // input projection + bias
    U8 fv2; fv2.u2 = *(const uint2*)(fpt + (size_t)s*4);
    __half2 f01 = fv2.h[0], f23 = fv2.h[1];
    __half2 ti = __hfma2(wxA.h[1], f23, __hmul2(wxA.h[0], f01));
    __half2 tf = __hfma2(wxA.h[3], f23, __hmul2(wxA.h[2], f01));
    __half2 tg = __hfma2(wxB.h[1], f23, __hmul2(wxB.h[0], f01));
    __half2 to = __hfma2(wxB.h[3], f23, __hmul2(wxB.h[2], f01));
    float gi = a0 + bsv.f[0] + __low2float(ti) + __high2float(ti);
    float gf = a1 + bsv.f[1] + __low2float(tf) + __high2float(tf);
    float gg = a2 + bsv.f[2] + __low2float(tg) + __high2float(tg);
    float go = a3 + bsv.f[3] + __low2float(to) + __high2float(to);

    float iv = sigmf_(gi), fvv = sigmf_(gf), gv = tanhf_(gg), ov2 = sigmf_(go);
    cst = fvv*cst + iv*gv;
    float hn = ov2 * tanhf_(cst);
    if (kh == 0){
      __half hf = __float2half(hn);
      hsh[buf^1][u] = hf;
      __builtin_nontemporal_store(*(f16*)&hf, hrow + u);   // keep L2 clean
    }
    hrow += HH;
    __syncthreads();
    buf ^= 1;
  }
}

// ----------------------------------------------------------------------------
// classifier: 16 rows per 256-thread block; 4x4 register tile per thread.
// packed f16 accumulate (__hfma2), flush to f32 every 32 k-pairs.
// ----------------------------------------------------------------------------
__device__ __forceinline__ void fc_layer(const __half2 (*src)[16], __half2 (*dst)[16],
                                         const f16* __restrict__ wt,
                                         const float* __restrict__ bias, int t)
{
  const int rg = t >> 6;           // row group 0..3
  const int c0 = (t & 63) * 4;     // 4 output cols
  float acc[4][4];
  #pragma unroll
  for (int r=0;r<4;r++){ acc[r][0]=0.f; acc[r][1]=0.f; acc[r][2]=0.f; acc[r][3]=0.f; }
  const __half2 z2 = __floats2half2_rn(0.f,0.f);
  #pragma unroll
  for (int blk=0; blk<4; ++blk){
    __half2 a16[4][4];
    #pragma unroll
    for (int r=0;r<4;r++)
      #pragma unroll
      for (int c=0;c<4;c++) a16[r][c] = z2;
    for (int kp=blk*32; kp<blk*32+32; kp++){
      U16 wv; wv.u4 = *(const uint4*)(wt + ((size_t)kp*256 + c0)*2);
      U16 rv; rv.u4 = *(const uint4*)(&src[kp][rg*4]);
      #pragma unroll
      for (int r=0;r<4;r++)
        #pragma unroll
        for (int c=0;c<4;c++)
          a16[r][c] = __hfma2(rv.h[r], wv.h[c], a16[r][c]);
    }
    #pragma unroll
    for (int r=0;r<4;r++)
      #pragma unroll
      for (int c=0;c<4;c++)
        acc[r][c] += __low2float(a16[r][c]) + __high2float(a16[r][c]);
  }
  const float4 bv = *(const float4*)(bias + c0);
  #pragma unroll
  for (int r=0;r<4;r++){
    float o0 = fmaxf(acc[r][0]+bv.x, 0.f);
    float o1 = fmaxf(acc[r][1]+bv.y, 0.f);
    float o2 = fmaxf(acc[r][2]+bv.z, 0.f);
    float o3 = fmaxf(acc[r][3]+bv.w, 0.f);
    dst[(c0>>1)  ][rg*4+r] = __floats2half2_rn(o0,o1);
    dst[(c0>>1)+1][rg*4+r] = __floats2half2_rn(o2,o3);
  }
}

__global__ __launch_bounds__(256) void cls_kernel(
    const f16* __restrict__ hbuf, const f16* __restrict__ w1t, const f16* __restrict__ w2t,
    const f16* __restrict__ w3p, const float* __restrict__ b1, const float* __restrict__ b2,
    const float* __restrict__ b3, float* __restrict__ out)
{
  __shared__ __align__(16) __half2 rlA[128][16];
  __shared__ __align__(16) __half2 rlB[128][16];
  const int t = threadIdx.x;
  const size_t R = (size_t)blockIdx.x * 16;
  {
    int r = t >> 4, seg = t & 15;
    const uint4* src = (const uint4*)(hbuf + (R + r)*HH + seg*16);
    U16 aH; aH.u4 = src[0];
    U16 bH; bH.u4 = src[1];
    int kp0 = seg*8;
    #pragma unroll
    for (int j=0;j<4;j++) rlA[kp0+j  ][r] = aH.h[j];
    #pragma unroll
    for (int j=0;j<4;j++) rlA[kp0+4+j][r] = bH.h[j];
  }
  __syncthreads();
  fc_layer(rlA, rlB, w1t, b1, t);
  __syncthreads();
  fc_layer(rlB, rlA, w2t, b2, t);
  __syncthreads();
  if (t < 32){
    int r = t >> 1, cls = t & 1;
    float acc = b3[cls];
    const __half2* w3h = (const __half2*)w3p;
    #pragma unroll 8
    for (int kp=0; kp<128; kp++){
      __half2 pr = __hmul2(rlA[kp][r], w3h[kp*2 + cls]);
      acc += __low2float(pr) + __high2float(pr);
    }
    out[(R + r)*2 + cls] = acc;
  }
}

// ----------------------------------------------------------------------------
extern "C" void kernel_launch(void* const* d_in, const int* in_sizes, int n_in,
                              void* d_out, int out_size, void* d_ws, size_t ws_size,
                              hipStream_t stream) {
  const float* x      = (const float*)d_in[0];
  const float* conv_w = (const float*)d_in[1];
  const float* conv_b = (const float*)d_in[2];
  const float* w_ih   = (const float*)d_in[3];
  const float* w_hh   = (const float*)d_in[4];
  const float* b_ih   = (const float*)d_in[5];
  const float* b_hh   = (const float*)d_in[6];
  const float* w1     = (const float*)d_in[7];
  const float* b1     = (const float*)d_in[8];
  const float* w2     = (const float*)d_in[9];
  const float* b2     = (const float*)d_in[10];
  const float* w3     = (const float*)d_in[11];
  const float* b3     = (const float*)d_in[12];

  char* ws = (char*)d_ws;
  f16*   feat2   = (f16*)  (ws + 0x000000);  // 1 MB
  uint4* wso     = (uint4*)(ws + 0x100000);  // 128 KB (o-gate stream)
  uint4* wxb     = (uint4*)(ws + 0x120000);  // 12 KB
  f16*   w1t     = (f16*)  (ws + 0x124000);  // 128 KB
  f16*   w2t     = (f16*)  (ws + 0x144000);  // 128 KB
  f16*   w3p     = (f16*)  (ws + 0x164000);  // 1 KB
  f16*   hbuf    = (f16*)  (ws + 0x170000);  // 64 MB

  prep_kernel<<<802, 256, 0, stream>>>(x, conv_w, conv_b, w_ih, w_hh, b_ih, b_hh,
                                       w1, w2, w3,
                                       feat2, wso, wxb, w1t, w2t, w3p);
  lstm_kernel<<<BB, 512, 0, stream>>>(w_hh, feat2, wso, wxb, hbuf);
  cls_kernel<<<(BB*SS)/16, 256, 0, stream>>>(hbuf, w1t, w2t, w3p, b1, b2, b3, (float*)d_out);
}

// Round 7
// 7035.676 us; speedup vs baseline: 1.5386x; 1.5386x over previous
//
#include <hip/hip_runtime.h>
#include <hip/hip_fp16.h>

// HybridQLSTM: B=64, S=2048, D=4, H=256, NCLS=2.
// R7 = R3 structure (1024 thr/block, i,f reg-resident, g in LDS, o streamed)
// with the three measured defects fixed:
//  - amdgpu_waves_per_eu(4,4): use full 128-VGPR budget, no AGPR/scratch spill
//  - __hfma2 packed math, f16 accum + 2 flushes (128 pk_fma vs ~384 cvt+fma)
//  - nontemporal hbuf stores so the 64MB write stream doesn't evict the
//    o-gate weight stream from L2 (R3: FETCH 8.4GB of pure re-fetch)

#define BB 64
#define SS 2048
#define HH 256

typedef _Float16 f16;

union U16 { uint4 u4; __half2 h[4]; float f[4]; f16 e[8]; };
union U8  { uint2 u2; __half2 h[2]; };

__device__ __forceinline__ float qsum4(float x){
#if __has_builtin(__builtin_amdgcn_mov_dpp)
  // quad_perm [1,0,3,2] = xor1 ; [2,3,0,1] = xor2
  x += __int_as_float(__builtin_amdgcn_mov_dpp(__float_as_int(x), 0xB1, 0xf, 0xf, true));
  x += __int_as_float(__builtin_amdgcn_mov_dpp(__float_as_int(x), 0x4E, 0xf, 0xf, true));
#else
  x += __shfl_xor(x, 1, 64);
  x += __shfl_xor(x, 2, 64);
#endif
  return x;
}

__device__ __forceinline__ float sigmf_(float x){ return 1.f/(1.f + __expf(-x)); }
__device__ __forceinline__ float tanhf_(float x){
  x = fminf(fmaxf(x, -15.f), 15.f);
  float e = __expf(2.f*x);
  return (e - 1.f)/(e + 1.f);
}

// ----------------------------------------------------------------------------
// prep job space: feat 131072 | wso 8192 | wxb 768 | w1t 32768 | w2t 32768 |
// w3p 256  => 205824 = 804*256.
// wso[c*1024 + t] (uint4): o-gate row 768+u (u=t>>2), cols kq*64+c*8.. (f16)
// wxb[u*3+0]: w_ih rows u,(u+256) f16; [+1]: rows 512+u,768+u; [+2]: bias f32x4.
// ----------------------------------------------------------------------------
__global__ void prep_kernel(
    const float* __restrict__ x, const float* __restrict__ conv_w, const float* __restrict__ conv_b,
    const float* __restrict__ w_ih, const float* __restrict__ w_hh,
    const float* __restrict__ b_ih, const float* __restrict__ b_hh,
    const float* __restrict__ w1, const float* __restrict__ w2, const float* __restrict__ w3,
    f16* __restrict__ feat2, uint4* __restrict__ wso, uint4* __restrict__ wxb,
    f16* __restrict__ w1t, f16* __restrict__ w2t, f16* __restrict__ w3p)
{
  int id = blockIdx.x*256 + threadIdx.x;
  if (id < BB*SS){
    float4 xv = *(const float4*)(x + (size_t)id*4);
    float f0 = sigmf_(xv.x*conv_w[0] + conv_b[0]);
    float f1 = sigmf_(xv.y*conv_w[1] + conv_b[1]);
    float f2 = sigmf_(xv.z*conv_w[2] + conv_b[2]);
    float f3 = sigmf_(xv.w*conv_w[3] + conv_b[3]);
    f16* o = feat2 + (size_t)id*4;
    o[0]=(f16)f0; o[1]=(f16)f1; o[2]=(f16)f2; o[3]=(f16)f3;
    return;
  }
  id -= BB*SS;
  if (id < 8192){
    int c = id >> 10, t = id & 1023;
    int u = t >> 2, kq = t & 3;
    const float* src = w_hh + (size_t)(768+u)*256 + kq*64 + c*8;
    U16 o;
    #pragma unroll
    for (int k=0;k<8;k++) o.e[k] = (f16)src[k];
    wso[id] = o.u4;
    return;
  }
  id -= 8192;
  if (id < 768){
    int u = id / 3, j = id - 3*(id/3);
    U16 o;
    if (j == 0){
      #pragma unroll
      for (int k=0;k<4;k++){ o.e[k] = (f16)w_ih[(size_t)u*4+k];
                             o.e[4+k] = (f16)w_ih[(size_t)(u+256)*4+k]; }
    } else if (j == 1){
      #pragma unroll
      for (int k=0;k<4;k++){ o.e[k] = (f16)w_ih[(size_t)(u+512)*4+k];
                             o.e[4+k] = (f16)w_ih[(size_t)(u+768)*4+k]; }
    } else {
      #pragma unroll
      for (int k=0;k<4;k++) o.f[k] = b_ih[u+256*k] + b_hh[u+256*k];
    }
    wxb[id] = o.u4;
    return;
  }
  id -= 768;
  if (id < 32768){
    int kp = id >> 8, n = id & 255;
    w1t[(size_t)id*2+0] = (f16)w1[(size_t)n*256 + 2*kp];
    w1t[(size_t)id*2+1] = (f16)w1[(size_t)n*256 + 2*kp+1];
    return;
  }
  id -= 32768;
  if (id < 32768){
    int kp = id >> 8, n = id & 255;
    w2t[(size_t)id*2+0] = (f16)w2[(size_t)n*256 + 2*kp];
    w2t[(size_t)id*2+1] = (f16)w2[(size_t)n*256 + 2*kp+1];
    return;
  }
  id -= 32768;
  if (id < 256){
    int kp = id >> 1, cls = id & 1;
    w3p[(size_t)id*2+0] = (f16)w3[(size_t)cls*256 + 2*kp];
    w3p[(size_t)id*2+1] = (f16)w3[(size_t)cls*256 + 2*kp+1];
  }
}

// ----------------------------------------------------------------------------
// LSTM: 64 blocks x 1024 threads. Thread t: unit u=t>>2, k-quarter kq=t&3.
// ----------------------------------------------------------------------------
#define GSEG 9   // uint4 per LDS g-segment (8 data + 1 pad)

__global__ __launch_bounds__(1024) __attribute__((amdgpu_waves_per_eu(4,4)))
void lstm_kernel(
    const float* __restrict__ w_hh, const f16* __restrict__ feat2,
    const uint4* __restrict__ wso, const uint4* __restrict__ wxb,
    f16* __restrict__ hbuf)
{
  extern __shared__ __align__(16) __half glds[];   // 1024*72 halves = 147456 B
  const int b = blockIdx.x, t = threadIdx.x;
  const int u = t >> 2, kq = t & 3;
  __shared__ __align__(16) __half hsh[2][4][72];   // padded quarters (R3: 0 conflicts)

  // resident i,f weights (rows u, u+256; k-quarter kq) as __half2 (64 VGPR)
  __half2 wr0[32], wr1[32];
  {
    const float* s0 = w_hh + (size_t)u*256 + kq*64;
    const float* s1 = w_hh + (size_t)(u+256)*256 + kq*64;
    #pragma unroll
    for (int c=0;c<8;c++){
      float4 a = *(const float4*)(s0 + c*8);
      float4 q = *(const float4*)(s0 + c*8 + 4);
      wr0[c*4+0] = __floats2half2_rn(a.x,a.y); wr0[c*4+1] = __floats2half2_rn(a.z,a.w);
      wr0[c*4+2] = __floats2half2_rn(q.x,q.y); wr0[c*4+3] = __floats2half2_rn(q.z,q.w);
      a = *(const float4*)(s1 + c*8);
      q = *(const float4*)(s1 + c*8 + 4);
      wr1[c*4+0] = __floats2half2_rn(a.x,a.y); wr1[c*4+1] = __floats2half2_rn(a.z,a.w);
      wr1[c*4+2] = __floats2half2_rn(q.x,q.y); wr1[c*4+3] = __floats2half2_rn(q.z,q.w);
    }
  }
  // g-gate weights -> LDS (row 512+u, quarter kq), one-time
  {
    const float* gsrc = w_hh + (size_t)(512+u)*256 + kq*64;
    uint4* gdst = (uint4*)glds + (size_t)t*GSEG;
    #pragma unroll
    for (int c=0;c<8;c++){
      float4 a = *(const float4*)(gsrc + c*8);
      float4 q = *(const float4*)(gsrc + c*8 + 4);
      U16 o;
      o.h[0] = __floats2half2_rn(a.x,a.y); o.h[1] = __floats2half2_rn(a.z,a.w);
      o.h[2] = __floats2half2_rn(q.x,q.y); o.h[3] = __floats2half2_rn(q.z,q.w);
      gdst[c] = o.u4;
    }
  }
  U16 wxA, wxB, bsv;
  wxA.u4 = wxb[u*3+0]; wxB.u4 = wxb[u*3+1]; bsv.u4 = wxb[u*3+2];

  if (t < 256) hsh[0][t>>6][t&63] = __float2half(0.f);
  __syncthreads();

  const uint4* wsoT = wso + t;                 // + c*1024 per chunk (o-gate)
  const uint4* gq   = (const uint4*)glds + (size_t)t*GSEG;
  const f16* fpt = feat2 + (size_t)b*SS*4;
  f16* hrow = hbuf + (size_t)b*SS*HH;
  float cst = 0.f;
  int buf = 0;
  const __half2 z2 = __floats2half2_rn(0.f,0.f);

  for (int s=0; s<SS; ++s){
    const uint4* hq = (const uint4*)(&hsh[buf][kq][0]);
    __half2 ai = z2, af = z2, ag = z2, ao = z2;
    float a0=0.f, a1=0.f, a2=0.f, a3=0.f;
    #pragma unroll
    for (int c=0;c<8;c++){
      U16 hv; hv.u4 = hq[c];
      U16 gv; gv.u4 = gq[c];
      U16 ov; ov.u4 = wsoT[(size_t)c*1024];   // short live range
      #pragma unroll
      for (int p=0;p<4;p++){
        ai = __hfma2(wr0[c*4+p], hv.h[p], ai);
        af = __hfma2(wr1[c*4+p], hv.h[p], af);
        ag = __hfma2(gv.h[p],    hv.h[p], ag);
        ao = __hfma2(ov.h[p],    hv.h[p], ao);
      }
      if (c == 3 || c == 7){  // flush every 32 terms
        a0 += __low2float(ai) + __high2float(ai); ai = z2;
        a1 += __low2float(af) + __high2float(af); af = z2;
        a2 += __low2float(ag) + __high2float(ag); ag = z2;
        a3 += __low2float(ao) + __high2float(ao); ao = z2;
      }
    }
    // reduce over the 4 k-quarters (quad lanes); replicated in quad
    a0 = qsum4(a0); a1 = qsum4(a1); a2 = qsum4(a2); a3 = qsum4(a3);

    // input projection + bias
    U8 fv2; fv2.u2 = *(const uint2*)(fpt + (size_t)s*4);
    __half2 f01 = fv2.h[0], f23 = fv2.h[1];
    __half2 ti = __hfma2(wxA.h[1], f23, __hmul2(wxA.h[0], f01));
    __half2 tf = __hfma2(wxA.h[3], f23, __hmul2(wxA.h[2], f01));
    __half2 tg = __hfma2(wxB.h[1], f23, __hmul2(wxB.h[0], f01));
    __half2 to = __hfma2(wxB.h[3], f23, __hmul2(wxB.h[2], f01));
    float gi = a0 + bsv.f[0] + __low2float(ti) + __high2float(ti);
    float gf = a1 + bsv.f[1] + __low2float(tf) + __high2float(tf);
    float gg = a2 + bsv.f[2] + __low2float(tg) + __high2float(tg);
    float go = a3 + bsv.f[3] + __low2float(to) + __high2float(to);

    float iv = sigmf_(gi), fvv = sigmf_(gf), gv2 = tanhf_(gg), ov2 = sigmf_(go);
    cst = fvv*cst + iv*gv2;
    float hn = ov2 * tanhf_(cst);
    if (kq == 0){
      __half hf = __float2half(hn);
      hsh[buf^1][u>>6][u&63] = hf;
      __builtin_nontemporal_store(*(f16*)&hf, hrow + u);  // keep o-stream in L2
    }
    hrow += HH;
    __syncthreads();
    buf ^= 1;
  }
}

// ----------------------------------------------------------------------------
// classifier: 16 rows per 256-thread block; 4x4 register tile per thread.
// ----------------------------------------------------------------------------
__device__ __forceinline__ void fc_layer(const __half2 (*src)[16], __half2 (*dst)[16],
                                         const f16* __restrict__ wt,
                                         const float* __restrict__ bias, int t)
{
  const int rg = t >> 6;           // row group 0..3
  const int c0 = (t & 63) * 4;     // 4 output cols
  float acc[4][4];
  #pragma unroll
  for (int r=0;r<4;r++){ acc[r][0]=0.f; acc[r][1]=0.f; acc[r][2]=0.f; acc[r][3]=0.f; }
  const __half2 z2 = __floats2half2_rn(0.f,0.f);
  #pragma unroll
  for (int blk=0; blk<4; ++blk){
    __half2 a16[4][4];
    #pragma unroll
    for (int r=0;r<4;r++)
      #pragma unroll
      for (int c=0;c<4;c++) a16[r][c] = z2;
    for (int kp=blk*32; kp<blk*32+32; kp++){
      U16 wv; wv.u4 = *(const uint4*)(wt + ((size_t)kp*256 + c0)*2);
      U16 rv; rv.u4 = *(const uint4*)(&src[kp][rg*4]);
      #pragma unroll
      for (int r=0;r<4;r++)
        #pragma unroll
        for (int c=0;c<4;c++)
          a16[r][c] = __hfma2(rv.h[r], wv.h[c], a16[r][c]);
    }
    #pragma unroll
    for (int r=0;r<4;r++)
      #pragma unroll
      for (int c=0;c<4;c++)
        acc[r][c] += __low2float(a16[r][c]) + __high2float(a16[r][c]);
  }
  const float4 bv = *(const float4*)(bias + c0);
  #pragma unroll
  for (int r=0;r<4;r++){
    float o0 = fmaxf(acc[r][0]+bv.x, 0.f);
    float o1 = fmaxf(acc[r][1]+bv.y, 0.f);
    float o2 = fmaxf(acc[r][2]+bv.z, 0.f);
    float o3 = fmaxf(acc[r][3]+bv.w, 0.f);
    dst[(c0>>1)  ][rg*4+r] = __floats2half2_rn(o0,o1);
    dst[(c0>>1)+1][rg*4+r] = __floats2half2_rn(o2,o3);
  }
}

__global__ __launch_bounds__(256) void cls_kernel(
    const f16* __restrict__ hbuf, const f16* __restrict__ w1t, const f16* __restrict__ w2t,
    const f16* __restrict__ w3p, const float* __restrict__ b1, const float* __restrict__ b2,
    const float* __restrict__ b3, float* __restrict__ out)
{
  __shared__ __align__(16) __half2 rlA[128][16];
  __shared__ __align__(16) __half2 rlB[128][16];
  const int t = threadIdx.x;
  const size_t R = (size_t)blockIdx.x * 16;
  {
    int r = t >> 4, seg = t & 15;
    const uint4* src = (const uint4*)(hbuf + (R + r)*HH + seg*16);
    U16 aH; aH.u4 = src[0];
    U16 bH; bH.u4 = src[1];
    int kp0 = seg*8;
    #pragma unroll
    for (int j=0;j<4;j++) rlA[kp0+j  ][r] = aH.h[j];
    #pragma unroll
    for (int j=0;j<4;j++) rlA[kp0+4+j][r] = bH.h[j];
  }
  __syncthreads();
  fc_layer(rlA, rlB, w1t, b1, t);
  __syncthreads();
  fc_layer(rlB, rlA, w2t, b2, t);
  __syncthreads();
  if (t < 32){
    int r = t >> 1, cls = t & 1;
    float acc = b3[cls];
    const __half2* w3h = (const __half2*)w3p;
    #pragma unroll 8
    for (int kp=0; kp<128; kp++){
      __half2 pr = __hmul2(rlA[kp][r], w3h[kp*2 + cls]);
      acc += __low2float(pr) + __high2float(pr);
    }
    out[(R + r)*2 + cls] = acc;
  }
}

// ----------------------------------------------------------------------------
extern "C" void kernel_launch(void* const* d_in, const int* in_sizes, int n_in,
                              void* d_out, int out_size, void* d_ws, size_t ws_size,
                              hipStream_t stream) {
  const float* x      = (const float*)d_in[0];
  const float* conv_w = (const float*)d_in[1];
  const float* conv_b = (const float*)d_in[2];
  const float* w_ih   = (const float*)d_in[3];
  const float* w_hh   = (const float*)d_in[4];
  const float* b_ih   = (const float*)d_in[5];
  const float* b_hh   = (const float*)d_in[6];
  const float* w1     = (const float*)d_in[7];
  const float* b1     = (const float*)d_in[8];
  const float* w2     = (const float*)d_in[9];
  const float* b2     = (const float*)d_in[10];
  const float* w3     = (const float*)d_in[11];
  const float* b3     = (const float*)d_in[12];

  char* ws = (char*)d_ws;
  f16*   feat2   = (f16*)  (ws + 0x000000);  // 1 MB
  uint4* wso     = (uint4*)(ws + 0x100000);  // 128 KB (o-gate stream)
  uint4* wxb     = (uint4*)(ws + 0x120000);  // 12 KB
  f16*   w1t     = (f16*)  (ws + 0x124000);  // 128 KB
  f16*   w2t     = (f16*)  (ws + 0x144000);  // 128 KB
  f16*   w3p     = (f16*)  (ws + 0x164000);  // 1 KB
  f16*   hbuf    = (f16*)  (ws + 0x170000);  // 64 MB

  const int glds_bytes = 1024 * 72 * sizeof(__half);  // 147456
  (void)hipFuncSetAttribute((const void*)lstm_kernel,
                            hipFuncAttributeMaxDynamicSharedMemorySize, glds_bytes);

  prep_kernel<<<804, 256, 0, stream>>>(x, conv_w, conv_b, w_ih, w_hh, b_ih, b_hh,
                                       w1, w2, w3,
                                       feat2, wso, wxb, w1t, w2t, w3p);
  lstm_kernel<<<BB, 1024, glds_bytes, stream>>>(w_hh, feat2, wso, wxb, hbuf);
  cls_kernel<<<(BB*SS)/16, 256, 0, stream>>>(hbuf, w1t, w2t, w3p, b1, b2, b3, (float*)d_out);
}